// Round 1
// baseline (1371.356 us; speedup 1.0000x reference)
//
#include <hip/hip_runtime.h>

// Problem constants (from reference setup_inputs)
constexpr int kB   = 32;
constexpr int kT   = 1002;
constexpr int kD   = 16;
constexpr int kE   = 32;
constexpr int kH   = 64;
constexpr int kLen = kT - 2;        // 1000
constexpr int kN   = kB * kLen;     // 32000
constexpr float kSlope = 0.2f;

// One thread = one (n, d) task. All threads in a block share d (blockIdx.y),
// so every weight access is wave-uniform -> scalar loads through the K$.
// Activations live in fully-unrolled register arrays; gates kept as sign
// bitmasks so the forward arrays can be reused by the Jacobian chain.
__global__ __launch_bounds__(256, 2) void np_prior_kernel(
    const float* __restrict__ x, const float* __restrict__ emb,
    const float* __restrict__ W0, const float* __restrict__ b0,
    const float* __restrict__ W1, const float* __restrict__ b1,
    const float* __restrict__ W2, const float* __restrict__ b2,
    const float* __restrict__ Wo, const float* __restrict__ bo,
    float* __restrict__ out_res, float* __restrict__ out_ld)
{
    const int n = blockIdx.x * blockDim.x + threadIdx.x;
    const int d = blockIdx.y;
    if (n >= kN) return;

    const int bb  = n / kLen;
    const int tt  = n - bb * kLen;
    const int src = bb * kT + tt + 2;   // time index offset by LAGS

    const float xv = x[(size_t)src * kD + d];
    const float* __restrict__ ep  = emb + (size_t)src * kE;

    const float* __restrict__ w0  = W0 + d * kH * (kE + 1);
    const float* __restrict__ w1  = W1 + d * kH * kH;
    const float* __restrict__ w2  = W2 + d * kH * kH;
    const float* __restrict__ wo  = Wo + d * kH;
    const float* __restrict__ pb0 = b0 + d * kH;
    const float* __restrict__ pb1 = b1 + d * kH;
    const float* __restrict__ pb2 = b2 + d * kH;

    // per-thread embedding row (dies after layer 0)
    float er[kE];
    #pragma unroll
    for (int e = 0; e < kE; ++e) er[e] = ep[e];

    float A[kH];   // ping
    float Bv[kH];  // pong
    unsigned int m0a = 0u, m0b = 0u, m1a = 0u, m1b = 0u, m2a = 0u, m2b = 0u;

    // ---- layer 0: z0 = W0 @ [emb, x] + b0 ----
    #pragma unroll
    for (int i = 0; i < kH; ++i) {
        float acc = pb0[i];
        const float* wr = w0 + i * (kE + 1);
        #pragma unroll
        for (int e = 0; e < kE; ++e) acc = fmaf(wr[e], er[e], acc);
        acc = fmaf(wr[kE], xv, acc);
        const bool g = (acc >= 0.f);
        if (i < 32) m0a |= (g ? 1u : 0u) << i; else m0b |= (g ? 1u : 0u) << (i - 32);
        A[i] = g ? acc : acc * kSlope;
    }

    // ---- layer 1 ----
    #pragma unroll
    for (int i = 0; i < kH; ++i) {
        float acc = pb1[i];
        const float* wr = w1 + i * kH;
        #pragma unroll
        for (int j = 0; j < kH; ++j) acc = fmaf(wr[j], A[j], acc);
        const bool g = (acc >= 0.f);
        if (i < 32) m1a |= (g ? 1u : 0u) << i; else m1b |= (g ? 1u : 0u) << (i - 32);
        Bv[i] = g ? acc : acc * kSlope;
    }

    // ---- layer 2 ----
    #pragma unroll
    for (int i = 0; i < kH; ++i) {
        float acc = pb2[i];
        const float* wr = w2 + i * kH;
        #pragma unroll
        for (int j = 0; j < kH; ++j) acc = fmaf(wr[j], Bv[j], acc);
        const bool g = (acc >= 0.f);
        if (i < 32) m2a |= (g ? 1u : 0u) << i; else m2b |= (g ? 1u : 0u) << (i - 32);
        A[i] = g ? acc : acc * kSlope;
    }

    // ---- output head ----
    float res = bo[d];
    #pragma unroll
    for (int h = 0; h < kH; ++h) res = fmaf(wo[h], A[h], res);

    // ---- Jacobian chain: t0 = g0 * W0[:, -1] ----
    #pragma unroll
    for (int i = 0; i < kH; ++i) {
        const unsigned int bit = (i < 32) ? ((m0a >> i) & 1u) : ((m0b >> (i - 32)) & 1u);
        const float g = bit ? 1.f : kSlope;
        A[i] = g * w0[i * (kE + 1) + kE];
    }
    // t1 = g1 * (W1 @ t0)
    #pragma unroll
    for (int i = 0; i < kH; ++i) {
        float acc = 0.f;
        const float* wr = w1 + i * kH;
        #pragma unroll
        for (int j = 0; j < kH; ++j) acc = fmaf(wr[j], A[j], acc);
        const unsigned int bit = (i < 32) ? ((m1a >> i) & 1u) : ((m1b >> (i - 32)) & 1u);
        Bv[i] = (bit ? 1.f : kSlope) * acc;
    }
    // t2 = g2 * (W2 @ t1)
    #pragma unroll
    for (int i = 0; i < kH; ++i) {
        float acc = 0.f;
        const float* wr = w2 + i * kH;
        #pragma unroll
        for (int j = 0; j < kH; ++j) acc = fmaf(wr[j], Bv[j], acc);
        const unsigned int bit = (i < 32) ? ((m2a >> i) & 1u) : ((m2b >> (i - 32)) & 1u);
        A[i] = (bit ? 1.f : kSlope) * acc;
    }
    // dJ = Wo @ t2
    float dj = 0.f;
    #pragma unroll
    for (int h = 0; h < kH; ++h) dj = fmaf(wo[h], A[h], dj);

    out_res[(size_t)n * kD + d] = res;
    atomicAdd(&out_ld[n], __logf(fabsf(dj)));
}

extern "C" void kernel_launch(void* const* d_in, const int* in_sizes, int n_in,
                              void* d_out, int out_size, void* d_ws, size_t ws_size,
                              hipStream_t stream) {
    const float* x  = (const float*)d_in[0];
    const float* em = (const float*)d_in[1];
    const float* W0 = (const float*)d_in[2];
    const float* b0 = (const float*)d_in[3];
    const float* W1 = (const float*)d_in[4];
    const float* b1 = (const float*)d_in[5];
    const float* W2 = (const float*)d_in[6];
    const float* b2 = (const float*)d_in[7];
    const float* Wo = (const float*)d_in[8];
    const float* bo = (const float*)d_in[9];

    float* out_res = (float*)d_out;                    // [N, D] residuals
    float* out_ld  = (float*)d_out + (size_t)kN * kD;  // [N] log|det J|

    // logdet is accumulated with atomics across the 16 d-blocks -> zero it first
    hipMemsetAsync(out_ld, 0, kN * sizeof(float), stream);

    dim3 grid(kN / 256, kD);
    np_prior_kernel<<<grid, dim3(256), 0, stream>>>(
        x, em, W0, b0, W1, b1, W2, b2, Wo, bo, out_res, out_ld);
}

// Round 2
// 740.317 us; speedup vs baseline: 1.8524x; 1.8524x over previous
//
#include <hip/hip_runtime.h>

// Problem constants (from reference setup_inputs)
constexpr int kB   = 32;
constexpr int kT   = 1002;
constexpr int kD   = 16;
constexpr int kE   = 32;
constexpr int kH   = 64;
constexpr int kLen = kT - 2;        // 1000
constexpr int kN   = kB * kLen;     // 32000
constexpr float kSlope = 0.2f;
constexpr int kTPB = 128;           // 32 KB LDS/block -> 5 blocks/CU

// One thread = one (n, d) task; all threads in a block share d (blockIdx.y)
// so weight reads are wave-uniform scalar loads. Layer boundaries route
// through LDS (thread-private column sbuf[h][tid]) instead of a second
// 64-float register array — this kills the round-1 scratch spill (300 MB
// of HBM traffic). Gates live as 64-bit sign masks so the Jacobian chain
// can reuse the same LDS buffer. No __syncthreads needed: each thread only
// touches its own column.
__global__ __launch_bounds__(kTPB, 2) void np_prior_kernel(
    const float* __restrict__ x, const float* __restrict__ emb,
    const float* __restrict__ W0, const float* __restrict__ b0,
    const float* __restrict__ W1, const float* __restrict__ b1,
    const float* __restrict__ W2, const float* __restrict__ b2,
    const float* __restrict__ Wo, const float* __restrict__ bo,
    float* __restrict__ out_res, float* __restrict__ out_ld)
{
    __shared__ float sbuf[kH][kTPB];   // [h][tid]: lane-consecutive -> conflict-free

    const int tid = threadIdx.x;
    const int n   = blockIdx.x * kTPB + tid;   // 250*128 == 32000 exactly
    const int d   = blockIdx.y;

    const int bb  = n / kLen;
    const int tt  = n - bb * kLen;
    const int src = bb * kT + tt + 2;          // LAGS offset

    const float xv = x[(size_t)src * kD + d];

    const float* __restrict__ w0  = W0 + d * kH * (kE + 1);
    const float* __restrict__ w1  = W1 + d * kH * kH;
    const float* __restrict__ w2  = W2 + d * kH * kH;
    const float* __restrict__ wo  = Wo + d * kH;
    const float* __restrict__ pb0 = b0 + d * kH;
    const float* __restrict__ pb1 = b1 + d * kH;
    const float* __restrict__ pb2 = b2 + d * kH;

    // embedding row: 8x float4 vector loads (row is 128 B aligned)
    float er[kE];
    const float4* __restrict__ ep4 =
        reinterpret_cast<const float4*>(emb + (size_t)src * kE);
    #pragma unroll
    for (int e4 = 0; e4 < kE / 4; ++e4) {
        float4 v = ep4[e4];
        er[4 * e4 + 0] = v.x; er[4 * e4 + 1] = v.y;
        er[4 * e4 + 2] = v.z; er[4 * e4 + 3] = v.w;
    }

    unsigned long long m0 = 0ull, m1 = 0ull, m2 = 0ull;

    // ---- L0: z0 = W0 @ [emb, x] + b0 -> gated to sbuf ----
    #pragma unroll 4
    for (int i = 0; i < kH; ++i) {
        float acc = pb0[i];
        const float* wr = w0 + i * (kE + 1);
        #pragma unroll
        for (int e = 0; e < kE; ++e) acc = fmaf(wr[e], er[e], acc);
        acc = fmaf(wr[kE], xv, acc);
        const bool g = (acc >= 0.f);
        m0 |= (unsigned long long)g << i;
        sbuf[i][tid] = g ? acc : acc * kSlope;
    }

    float a[kH];

    // ---- L1 ----
    #pragma unroll
    for (int j = 0; j < kH; ++j) a[j] = sbuf[j][tid];
    #pragma unroll 4
    for (int i = 0; i < kH; ++i) {
        float acc = pb1[i];
        const float* wr = w1 + i * kH;
        #pragma unroll
        for (int j = 0; j < kH; ++j) acc = fmaf(wr[j], a[j], acc);
        const bool g = (acc >= 0.f);
        m1 |= (unsigned long long)g << i;
        sbuf[i][tid] = g ? acc : acc * kSlope;
    }

    // ---- L2 + fused output head (a2 never stored; sign kept in m2) ----
    #pragma unroll
    for (int j = 0; j < kH; ++j) a[j] = sbuf[j][tid];
    float res = bo[d];
    #pragma unroll 4
    for (int i = 0; i < kH; ++i) {
        float acc = pb2[i];
        const float* wr = w2 + i * kH;
        #pragma unroll
        for (int j = 0; j < kH; ++j) acc = fmaf(wr[j], a[j], acc);
        const bool g = (acc >= 0.f);
        m2 |= (unsigned long long)g << i;
        res = fmaf(wo[i], g ? acc : acc * kSlope, res);
    }

    // ---- Jacobian chain: t0 = g0 * W0[:, -1] -> sbuf ----
    #pragma unroll 4
    for (int i = 0; i < kH; ++i) {
        const float g = ((m0 >> i) & 1ull) ? 1.f : kSlope;
        sbuf[i][tid] = g * w0[i * (kE + 1) + kE];
    }

    // ---- jac L1: t1 = g1 * (W1 @ t0) -> sbuf ----
    #pragma unroll
    for (int j = 0; j < kH; ++j) a[j] = sbuf[j][tid];
    #pragma unroll 4
    for (int i = 0; i < kH; ++i) {
        float acc = 0.f;
        const float* wr = w1 + i * kH;
        #pragma unroll
        for (int j = 0; j < kH; ++j) acc = fmaf(wr[j], a[j], acc);
        sbuf[i][tid] = (((m1 >> i) & 1ull) ? 1.f : kSlope) * acc;
    }

    // ---- jac L2 + fused head: dJ = Wo @ (g2 * (W2 @ t1)) ----
    #pragma unroll
    for (int j = 0; j < kH; ++j) a[j] = sbuf[j][tid];
    float dj = 0.f;
    #pragma unroll 4
    for (int i = 0; i < kH; ++i) {
        float acc = 0.f;
        const float* wr = w2 + i * kH;
        #pragma unroll
        for (int j = 0; j < kH; ++j) acc = fmaf(wr[j], a[j], acc);
        dj = fmaf(wo[i], (((m2 >> i) & 1ull) ? 1.f : kSlope) * acc, dj);
    }

    out_res[(size_t)n * kD + d] = res;
    atomicAdd(&out_ld[n], __logf(fabsf(dj)));
}

extern "C" void kernel_launch(void* const* d_in, const int* in_sizes, int n_in,
                              void* d_out, int out_size, void* d_ws, size_t ws_size,
                              hipStream_t stream) {
    const float* x  = (const float*)d_in[0];
    const float* em = (const float*)d_in[1];
    const float* W0 = (const float*)d_in[2];
    const float* b0 = (const float*)d_in[3];
    const float* W1 = (const float*)d_in[4];
    const float* b1 = (const float*)d_in[5];
    const float* W2 = (const float*)d_in[6];
    const float* b2 = (const float*)d_in[7];
    const float* Wo = (const float*)d_in[8];
    const float* bo = (const float*)d_in[9];

    float* out_res = (float*)d_out;                    // [N, D] residuals
    float* out_ld  = (float*)d_out + (size_t)kN * kD;  // [N] log|det J|

    // logdet accumulated with atomics across the 16 d-blocks -> zero it first
    hipMemsetAsync(out_ld, 0, kN * sizeof(float), stream);

    dim3 grid(kN / kTPB, kD);
    np_prior_kernel<<<grid, dim3(kTPB), 0, stream>>>(
        x, em, W0, b0, W1, b1, W2, b2, Wo, bo, out_res, out_ld);
}